// Round 2
// baseline (671.718 us; speedup 1.0000x reference)
//
#include <hip/hip_runtime.h>
#include <hip/hip_bf16.h>
#include <stdint.h>

// Problem constants (fixed by setup_inputs)
#define TT 2048
#define BB 64
#define VV 256
#define SS 256
#define LL 513

__device__ __forceinline__ float exp2_fast(float x) {
  float r; asm("v_exp_f32 %0, %1" : "=v"(r) : "v"(x)); return r;
}
__device__ __forceinline__ float log2_fast(float x) {
  float r; asm("v_log_f32 %0, %1" : "=v"(r) : "v"(x)); return r;
}
__device__ __forceinline__ void g2l16(const void* g, void* l) {
  __builtin_amdgcn_global_load_lds((const __attribute__((address_space(1))) void*)g,
                                   (__attribute__((address_space(3))) void*)l, 16, 0, 0);
}

#define F_L2E 1.4426950408889634f
#define F_LN2 0.6931471805599453f

// ---------------- Phase 1: per-(t,b) row max (scaled to log2) and -log2(Z) ----------------
__global__ __launch_bounds__(256) void k_rowstats(const float* __restrict__ lp,
                                                  float* __restrict__ M2T,
                                                  float* __restrict__ D2T) {
  int row  = blockIdx.x * 4 + (threadIdx.x >> 6);   // row = t*BB + b
  int lane = threadIdx.x & 63;
  float4 x = reinterpret_cast<const float4*>(lp + (size_t)row * VV)[lane];
  float m = fmaxf(fmaxf(x.x, x.y), fmaxf(x.z, x.w));
  m = fmaxf(m, __shfl_xor(m, 1));
  m = fmaxf(m, __shfl_xor(m, 2));
  m = fmaxf(m, __shfl_xor(m, 4));
  m = fmaxf(m, __shfl_xor(m, 8));
  m = fmaxf(m, __shfl_xor(m, 16));
  m = fmaxf(m, __shfl_xor(m, 32));
  float z = exp2_fast((x.x - m) * F_L2E) + exp2_fast((x.y - m) * F_L2E)
          + exp2_fast((x.z - m) * F_L2E) + exp2_fast((x.w - m) * F_L2E);
  z += __shfl_xor(z, 1);
  z += __shfl_xor(z, 2);
  z += __shfl_xor(z, 4);
  z += __shfl_xor(z, 8);
  z += __shfl_xor(z, 16);
  z += __shfl_xor(z, 32);
  if (lane == 0) {
    int t = row >> 6;     // / BB
    int b = row & 63;     // % BB
    M2T[(size_t)b * TT + t] = m * F_L2E;
    D2T[(size_t)b * TT + t] = -log2_fast(z);
  }
}

// ---------------- Phase 2: linear-domain CTC DP, one wave per batch ----------------
// Alphas carry a 2^{+100} bias (re-established every 8 steps) so that path mass
// up to ~134 nats below the running band max stays representable in f32
// (denormal-flush floor 2^-126). The exact exponent is carried in C.
__global__ __launch_bounds__(64) void k_ctc(const float* __restrict__ lp,
                                            const int* __restrict__ tgt,
                                            const int* __restrict__ ilen,
                                            const int* __restrict__ tlen,
                                            const float* __restrict__ M2T,
                                            const float* __restrict__ D2T,
                                            float* __restrict__ lossw) {
  __shared__ float rowbuf[16][VV];   // 16 KB ring of staged log-prob rows
  __shared__ float mdf[1024];        // [chunk parity][ {M2, D2} ][256]
  __shared__ float afin[LL];

  int b    = blockIdx.x;
  int lane = threadIdx.x;
  int len  = ilen[b]; if (len > TT) len = TT;
  int tl   = tlen[b];

  const float* rowb = lp  + (size_t)b * VV + lane * 4; // + t*BB*VV per step
  const float* m2b  = M2T + (size_t)b * TT;
  const float* d2b  = D2T + (size_t)b * TT;

  // per-lane target slice: s = 4*lane .. 4*lane+3 (odd positions 8*lane+1,3,5,7)
  int4 tv = reinterpret_cast<const int4*>(tgt + b * SS)[lane];
  int pw  = __shfl_up(tv.w, 1);
  float mk1 = (lane > 0 && tv.x != pw)   ? 1.f : 0.f;
  float mk3 = (tv.y != tv.x)             ? 1.f : 0.f;
  float mk5 = (tv.z != tv.y)             ? 1.f : 0.f;
  float mk7 = (tv.w != tv.z)             ? 1.f : 0.f;
  int o1 = tv.x, o3 = tv.y, o5 = tv.z, o7 = tv.w;

  // prologue: md chunk 0 first, then rows 0..13 (14 in flight)
  g2l16(m2b + lane * 4, &mdf[0]);
  g2l16(d2b + lane * 4, &mdf[256]);
#pragma unroll
  for (int r = 0; r < 14; ++r)
    g2l16(rowb + (size_t)r * (BB * VV), &rowbuf[r][0]);

  // virtual pre-state: alpha_{-1} = 2^100 * delta(l==0); first loop iter builds alpha_0
  float a0 = (lane == 0) ? __uint_as_float((unsigned)(127 + 100) << 23) : 0.f;
  float a1 = 0.f, a2 = 0.f, a3 = 0.f, a4 = 0.f, a5 = 0.f, a6 = 0.f, a7 = 0.f, a8 = 0.f;
  float C = -100.f;   // accounts for the 2^100 bias in the initial alpha

#define STEP(t_, slot_, cp_) do {                                              \
    asm volatile("s_waitcnt vmcnt(13)" ::: "memory");                          \
    float h1 = __shfl_up(a7, 1);                                               \
    if (lane == 0) h1 = 0.f;                                                   \
    int idx_ = (t_) & 255;                                                     \
    float m2 = mdf[(cp_) * 512 + idx_];                                        \
    float d2 = mdf[(cp_) * 512 + 256 + idx_];                                  \
    const float* rb_ = &rowbuf[(slot_)][0];                                    \
    float eb = rb_[0];                                                         \
    float e1 = rb_[o1], e3 = rb_[o3], e5 = rb_[o5], e7 = rb_[o7];              \
    int tn_ = (t_) + 14; if (tn_ > TT - 1) tn_ = TT - 1;                       \
    g2l16(rowb + (size_t)tn_ * (BB * VV), &rowbuf[((slot_) + 14) & 15][0]);    \
    float pb = exp2_fast(fmaf(eb, F_L2E, -m2));                                \
    float p1 = exp2_fast(fmaf(e1, F_L2E, -m2));                                \
    float p3 = exp2_fast(fmaf(e3, F_L2E, -m2));                                \
    float p5 = exp2_fast(fmaf(e5, F_L2E, -m2));                                \
    float p7 = exp2_fast(fmaf(e7, F_L2E, -m2));                                \
    a8 = (a8 + a7) * pb;                                                       \
    a7 = (a7 + a6 + mk7 * a5) * p7;                                            \
    a6 = (a6 + a5) * pb;                                                       \
    a5 = (a5 + a4 + mk5 * a3) * p5;                                            \
    a4 = (a4 + a3) * pb;                                                       \
    a3 = (a3 + a2 + mk3 * a1) * p3;                                            \
    a2 = (a2 + a1) * pb;                                                       \
    a1 = (a1 + a0 + mk1 * h1) * p1;                                            \
    a0 = (a0 + h1) * pb;                                                       \
    C += d2;                                                                   \
  } while (0)

  // Rescale band max back to 2^{+100}; exact exponent moved into C.
#define RESCALE() do {                                                         \
    float mx = fmaxf(fmaxf(fmaxf(a0, a1), fmaxf(a2, a3)),                      \
                     fmaxf(fmaxf(a4, a5), fmaxf(fmaxf(a6, a7), a8)));          \
    mx = fmaxf(mx, __shfl_xor(mx, 1));                                         \
    mx = fmaxf(mx, __shfl_xor(mx, 2));                                         \
    mx = fmaxf(mx, __shfl_xor(mx, 4));                                         \
    mx = fmaxf(mx, __shfl_xor(mx, 8));                                         \
    mx = fmaxf(mx, __shfl_xor(mx, 16));                                        \
    mx = fmaxf(mx, __shfl_xor(mx, 32));                                        \
    int e_ = (int)((__float_as_uint(mx) >> 23) & 255) - 127;                   \
    int dl_ = 100 - e_;                                                        \
    if (dl_ > 127) dl_ = 127;                                                  \
    if (dl_ < -126) dl_ = -126;                                                \
    float sc = __uint_as_float((unsigned)(127 + dl_) << 23);                   \
    a0 *= sc; a1 *= sc; a2 *= sc; a3 *= sc; a4 *= sc;                          \
    a5 *= sc; a6 *= sc; a7 *= sc; a8 *= sc;                                    \
    C += (float)(-dl_);                                                        \
  } while (0)

  int t = 0;
  for (int c = 0; c < TT / 256 && t < len; ++c) {
    int cp = c & 1;
    if (c + 1 < TT / 256) {   // prefetch next md chunk
      g2l16(m2b + (c + 1) * 256 + lane * 4, &mdf[(cp ^ 1) * 512]);
      g2l16(d2b + (c + 1) * 256 + lane * 4, &mdf[(cp ^ 1) * 512 + 256]);
    }
    for (int u = 0; u < 16 && t + 16 <= len; ++u) {
      STEP(t + 0, 0, cp);  STEP(t + 1, 1, cp);  STEP(t + 2, 2, cp);  STEP(t + 3, 3, cp);
      STEP(t + 4, 4, cp);  STEP(t + 5, 5, cp);  STEP(t + 6, 6, cp);  STEP(t + 7, 7, cp);
      RESCALE();
      STEP(t + 8, 8, cp);  STEP(t + 9, 9, cp);  STEP(t + 10, 10, cp); STEP(t + 11, 11, cp);
      STEP(t + 12, 12, cp); STEP(t + 13, 13, cp); STEP(t + 14, 14, cp); STEP(t + 15, 15, cp);
      RESCALE();
      t += 16;
    }
  }
  // tail (len not multiple of 16) — dynamic slot
  while (t < len) { int sl = t & 15; int cp = (t >> 8) & 1; STEP(t, sl, cp); ++t; RESCALE(); }

  // dump alpha, extract endpoints
  afin[8 * lane + 0] = a0; afin[8 * lane + 1] = a1;
  afin[8 * lane + 2] = a2; afin[8 * lane + 3] = a3;
  afin[8 * lane + 4] = a4; afin[8 * lane + 5] = a5;
  afin[8 * lane + 6] = a6; afin[8 * lane + 7] = a7;
  if (lane == 63) afin[512] = a8;
  __syncthreads();
  if (lane == 0) {
    float ssum = afin[2 * tl] + afin[2 * tl - 1];
    lossw[b] = -F_LN2 * (log2_fast(ssum) + C);   // natural-log loss
  }
#undef STEP
#undef RESCALE
}

// ---------------- Phase 3: zero_infinity guard, /tl, mean ----------------
__global__ __launch_bounds__(64) void k_final(const float* __restrict__ lossw,
                                              const int* __restrict__ tlen,
                                              float* __restrict__ out) {
  int i = threadIdx.x;
  float v = lossw[i];
  float d = (float)tlen[i];
  v = (v < 1e29f && v > -1e30f) ? (v / d) : 0.f;   // NaN/±inf -> 0
  v += __shfl_xor(v, 1);
  v += __shfl_xor(v, 2);
  v += __shfl_xor(v, 4);
  v += __shfl_xor(v, 8);
  v += __shfl_xor(v, 16);
  v += __shfl_xor(v, 32);
  if (i == 0) out[0] = v * (1.f / BB);
}

extern "C" void kernel_launch(void* const* d_in, const int* in_sizes, int n_in,
                              void* d_out, int out_size, void* d_ws, size_t ws_size,
                              hipStream_t stream) {
  const float* lp  = (const float*)d_in[0];
  const int* tgt   = (const int*)d_in[1];
  const int* ilen  = (const int*)d_in[2];
  const int* tlen  = (const int*)d_in[3];
  float* M2T  = (float*)d_ws;                       // [B][T]
  float* D2T  = M2T + (size_t)BB * TT;              // [B][T]
  float* lossw = D2T + (size_t)BB * TT;             // [B]
  k_rowstats<<<TT * BB / 4, 256, 0, stream>>>(lp, M2T, D2T);
  k_ctc<<<BB, 64, 0, stream>>>(lp, tgt, ilen, tlen, M2T, D2T, lossw);
  k_final<<<1, 64, 0, stream>>>(lossw, tlen, (float*)d_out);
}

// Round 3
// 294.572 us; speedup vs baseline: 2.2803x; 2.2803x over previous
//
#include <hip/hip_runtime.h>
#include <hip/hip_bf16.h>
#include <hip/hip_fp16.h>
#include <stdint.h>

// Problem constants (fixed by setup_inputs)
#define TT 2048
#define BB 64
#define VV 256
#define SS 256
#define LL 513
#define ROWB  (BB * VV * 2)   // bytes between row (t,b) and (t+1,b) in E: 32768
#define PAIRB (2 * ROWB)      // 65536

#define F_L2E 1.4426950408889634f
#define F_LN2 0.6931471805599453f

__device__ __forceinline__ float exp2_fast(float x) {
  float r; asm("v_exp_f32 %0, %1" : "=v"(r) : "v"(x)); return r;
}
__device__ __forceinline__ float log2_fast(float x) {
  float r; asm("v_log_f32 %0, %1" : "=v"(r) : "v"(x)); return r;
}
__device__ __forceinline__ void g2l16(const void* g, void* l) {
  __builtin_amdgcn_global_load_lds((const __attribute__((address_space(1))) void*)g,
                                   (__attribute__((address_space(3))) void*)l, 16, 0, 0);
}

// =====================================================================
// NEW PATH: phase 1 writes E = exp(lp) (fp16) + D2 = -log2(sum exp(row))
// =====================================================================
__global__ __launch_bounds__(256) void k_prep(const float* __restrict__ lp,
                                              __half* __restrict__ E,
                                              float* __restrict__ D2T) {
  int row  = blockIdx.x * 4 + (threadIdx.x >> 6);   // row = t*BB + b
  int lane = threadIdx.x & 63;
  float4 x = reinterpret_cast<const float4*>(lp + (size_t)row * VV)[lane];
  float e0 = exp2_fast(x.x * F_L2E), e1 = exp2_fast(x.y * F_L2E);
  float e2 = exp2_fast(x.z * F_L2E), e3 = exp2_fast(x.w * F_L2E);
  float z = (e0 + e1) + (e2 + e3);
  z += __shfl_xor(z, 1);
  z += __shfl_xor(z, 2);
  z += __shfl_xor(z, 4);
  z += __shfl_xor(z, 8);
  z += __shfl_xor(z, 16);
  z += __shfl_xor(z, 32);
  union { __half2 h[2]; uint2 u; } pk;
  pk.h[0] = __floats2half2_rn(e0, e1);
  pk.h[1] = __floats2half2_rn(e2, e3);
  reinterpret_cast<uint2*>(E + (size_t)row * VV)[lane] = pk.u;
  if (lane == 0) {
    int t = row >> 6, b = row & 63;
    D2T[(size_t)b * TT + t] = -log2_fast(z);
  }
}

// Phase 2: linear-domain CTC DP on precomputed fp16 exp-table.
// One wave per batch; 16-step blocks, double-buffered LDS, one vmcnt wait per block.
__global__ __launch_bounds__(64) void k_ctc2(const __half* __restrict__ E,
                                             const int* __restrict__ tgt,
                                             const int* __restrict__ ilen,
                                             const int* __restrict__ tlen,
                                             const float* __restrict__ D2T,
                                             float* __restrict__ lossw) {
  __shared__ __half rowlds[8192];  // 2 buffers x 16 rows x 256 halves = 16 KB
  __shared__ float afin[LL];

  int b    = blockIdx.x;
  int lane = threadIdx.x;
  int len  = ilen[b]; if (len > TT) len = TT;
  int tl   = tlen[b];

  const float* d2b = D2T + (size_t)b * TT;
  // per-lane source for double-row loads: lanes 0-31 -> row t, lanes 32-63 -> row t+1
  const char* esrc = (const char*)E + (size_t)b * VV * 2
                   + (size_t)(lane & 31) * 16 + (size_t)(lane >> 5) * ROWB;

  // per-lane target slice: cells 8*lane+{1,3,5,7} have classes tv.{x,y,z,w}
  int4 tv = reinterpret_cast<const int4*>(tgt + b * SS)[lane];
  int pw  = __shfl_up(tv.w, 1);
  float mk1 = (lane > 0 && tv.x != pw) ? 1.f : 0.f;
  float mk3 = (tv.y != tv.x) ? 1.f : 0.f;
  float mk5 = (tv.z != tv.y) ? 1.f : 0.f;
  float mk7 = (tv.w != tv.z) ? 1.f : 0.f;
  int o1 = tv.x, o3 = tv.y, o5 = tv.z, o7 = tv.w;

  // alpha with 2^30 bias; exponent carried (uniformly) in C
  float a0 = (lane == 0) ? __uint_as_float((unsigned)(127 + 30) << 23) : 0.f;
  float a1 = 0.f, a2 = 0.f, a3 = 0.f, a4 = 0.f, a5 = 0.f, a6 = 0.f, a7 = 0.f, a8 = 0.f;
  float C = -30.f;

#define ISSUE_BLOCK(kk_, bid_) do {                                            \
    int p0_ = (kk_) * 8;                                                       \
    _Pragma("unroll")                                                          \
    for (int p_ = 0; p_ < 8; ++p_) {                                           \
      int pi_ = p0_ + p_; if (pi_ > TT / 2 - 1) pi_ = TT / 2 - 1;              \
      g2l16(esrc + (size_t)pi_ * PAIRB, (void*)&rowlds[(bid_) * 4096 + p_ * 512]); \
    }                                                                          \
  } while (0)

#define STEP(r_, bid_) do {                                                    \
    const int IB = (bid_) * 4096 + (r_) * 256;                                 \
    float pb = __half2float(rowlds[IB]);                                       \
    float q1 = __half2float(rowlds[IB + o1]);                                  \
    float q3 = __half2float(rowlds[IB + o3]);                                  \
    float q5 = __half2float(rowlds[IB + o5]);                                  \
    float q7 = __half2float(rowlds[IB + o7]);                                  \
    float h1 = __shfl_up(a7, 1);                                               \
    h1 = (lane == 0) ? 0.f : h1;                                               \
    a8 = (a8 + a7) * pb;                                                       \
    a7 = (a7 + a6 + mk7 * a5) * q7;                                            \
    a6 = (a6 + a5) * pb;                                                       \
    a5 = (a5 + a4 + mk5 * a3) * q5;                                            \
    a4 = (a4 + a3) * pb;                                                       \
    a3 = (a3 + a2 + mk3 * a1) * q3;                                            \
    a2 = (a2 + a1) * pb;                                                       \
    a1 = (a1 + a0 + mk1 * h1) * q1;                                            \
    a0 = (a0 + h1) * pb;                                                       \
  } while (0)

#define DPPMAX(ctrl_) do {                                                     \
    int d_ = __builtin_amdgcn_update_dpp(__float_as_int(mx), __float_as_int(mx), \
                                         (ctrl_), 0xF, 0xF, false);            \
    mx = fmaxf(mx, __int_as_float(d_));                                        \
  } while (0)

  // band-max rescale to 2^30 via DPP reduction (VALU-only); exponent into C
#define RESCALE() do {                                                         \
    float mx = fmaxf(fmaxf(fmaxf(a0, a1), fmaxf(a2, a3)),                      \
                     fmaxf(fmaxf(a4, a5), fmaxf(fmaxf(a6, a7), a8)));          \
    DPPMAX(0x111); DPPMAX(0x112); DPPMAX(0x114); DPPMAX(0x118);                \
    DPPMAX(0x142); DPPMAX(0x143);                                              \
    int eb_ = (__builtin_amdgcn_readlane(__float_as_int(mx), 63) >> 23) & 255; \
    int se_ = 284 - eb_; if (se_ < 1) se_ = 1; if (se_ > 254) se_ = 254;       \
    float sc_ = __uint_as_float((unsigned)se_ << 23);                          \
    a0 *= sc_; a1 *= sc_; a2 *= sc_; a3 *= sc_; a4 *= sc_;                     \
    a5 *= sc_; a6 *= sc_; a7 *= sc_; a8 *= sc_;                                \
    C += (float)(127 - se_);                                                   \
  } while (0)

#define BLOCK(kk_, bid_) do {                                                  \
    if (tcur + 16 <= len) {                                                    \
      ISSUE_BLOCK((kk_) + 1, (bid_) ^ 1);                                      \
      asm volatile("s_waitcnt vmcnt(8)" ::: "memory");                         \
      STEP(0, bid_);  STEP(1, bid_);  STEP(2, bid_);  STEP(3, bid_);           \
      STEP(4, bid_);  STEP(5, bid_);  STEP(6, bid_);  STEP(7, bid_);           \
      RESCALE();                                                               \
      STEP(8, bid_);  STEP(9, bid_);  STEP(10, bid_); STEP(11, bid_);          \
      STEP(12, bid_); STEP(13, bid_); STEP(14, bid_); STEP(15, bid_);          \
      RESCALE();                                                               \
      tcur += 16;                                                              \
    }                                                                          \
  } while (0)

  ISSUE_BLOCK(0, 0);
  int tcur = 0;
  for (int g = 0; g < TT / 32; ++g) {
    BLOCK(2 * g, 0);
    BLOCK(2 * g + 1, 1);
  }

  // generic tail (len not a multiple of 16) — data resident, drain and go slow
  if (tcur < len) {
    asm volatile("s_waitcnt vmcnt(0)" ::: "memory");
    while (tcur < len) {
      int ib = ((tcur >> 4) & 1) * 4096 + (tcur & 15) * 256;
      float pb = __half2float(rowlds[ib]);
      float q1 = __half2float(rowlds[ib + o1]);
      float q3 = __half2float(rowlds[ib + o3]);
      float q5 = __half2float(rowlds[ib + o5]);
      float q7 = __half2float(rowlds[ib + o7]);
      float h1 = __shfl_up(a7, 1);
      h1 = (lane == 0) ? 0.f : h1;
      a8 = (a8 + a7) * pb;
      a7 = (a7 + a6 + mk7 * a5) * q7;
      a6 = (a6 + a5) * pb;
      a5 = (a5 + a4 + mk5 * a3) * q5;
      a4 = (a4 + a3) * pb;
      a3 = (a3 + a2 + mk3 * a1) * q3;
      a2 = (a2 + a1) * pb;
      a1 = (a1 + a0 + mk1 * h1) * q1;
      a0 = (a0 + h1) * pb;
      ++tcur;
      RESCALE();
    }
  }

  // normalization constant: sum of -log2(Z_t) over t < len
  float dsm = 0.f;
  for (int k2 = 0; k2 < TT / 64; ++k2) {
    int t2 = lane + 64 * k2;
    if (t2 < len) dsm += d2b[t2];
  }
  dsm += __shfl_xor(dsm, 1);
  dsm += __shfl_xor(dsm, 2);
  dsm += __shfl_xor(dsm, 4);
  dsm += __shfl_xor(dsm, 8);
  dsm += __shfl_xor(dsm, 16);
  dsm += __shfl_xor(dsm, 32);

  afin[8 * lane + 0] = a0; afin[8 * lane + 1] = a1;
  afin[8 * lane + 2] = a2; afin[8 * lane + 3] = a3;
  afin[8 * lane + 4] = a4; afin[8 * lane + 5] = a5;
  afin[8 * lane + 6] = a6; afin[8 * lane + 7] = a7;
  if (lane == 63) afin[512] = a8;
  __syncthreads();
  if (lane == 0) {
    float ssum = afin[2 * tl] + afin[2 * tl - 1];
    lossw[b] = -F_LN2 * (log2_fast(ssum) + C + dsm);
  }
#undef BLOCK
#undef RESCALE
#undef DPPMAX
#undef STEP
#undef ISSUE_BLOCK
}

// =====================================================================
// FALLBACK PATH (R2, known-correct): used only if ws_size is too small
// =====================================================================
__global__ __launch_bounds__(256) void k_rowstats(const float* __restrict__ lp,
                                                  float* __restrict__ M2T,
                                                  float* __restrict__ D2T) {
  int row  = blockIdx.x * 4 + (threadIdx.x >> 6);
  int lane = threadIdx.x & 63;
  float4 x = reinterpret_cast<const float4*>(lp + (size_t)row * VV)[lane];
  float m = fmaxf(fmaxf(x.x, x.y), fmaxf(x.z, x.w));
  m = fmaxf(m, __shfl_xor(m, 1));
  m = fmaxf(m, __shfl_xor(m, 2));
  m = fmaxf(m, __shfl_xor(m, 4));
  m = fmaxf(m, __shfl_xor(m, 8));
  m = fmaxf(m, __shfl_xor(m, 16));
  m = fmaxf(m, __shfl_xor(m, 32));
  float z = exp2_fast((x.x - m) * F_L2E) + exp2_fast((x.y - m) * F_L2E)
          + exp2_fast((x.z - m) * F_L2E) + exp2_fast((x.w - m) * F_L2E);
  z += __shfl_xor(z, 1);
  z += __shfl_xor(z, 2);
  z += __shfl_xor(z, 4);
  z += __shfl_xor(z, 8);
  z += __shfl_xor(z, 16);
  z += __shfl_xor(z, 32);
  if (lane == 0) {
    int t = row >> 6, b = row & 63;
    M2T[(size_t)b * TT + t] = m * F_L2E;
    D2T[(size_t)b * TT + t] = -log2_fast(z);
  }
}

__global__ __launch_bounds__(64) void k_ctc(const float* __restrict__ lp,
                                            const int* __restrict__ tgt,
                                            const int* __restrict__ ilen,
                                            const int* __restrict__ tlen,
                                            const float* __restrict__ M2T,
                                            const float* __restrict__ D2T,
                                            float* __restrict__ lossw) {
  __shared__ float rowbuf[16][VV];
  __shared__ float mdf[1024];
  __shared__ float afin[LL];

  int b    = blockIdx.x;
  int lane = threadIdx.x;
  int len  = ilen[b]; if (len > TT) len = TT;
  int tl   = tlen[b];

  const float* rowb = lp  + (size_t)b * VV + lane * 4;
  const float* m2b  = M2T + (size_t)b * TT;
  const float* d2b  = D2T + (size_t)b * TT;

  int4 tv = reinterpret_cast<const int4*>(tgt + b * SS)[lane];
  int pw  = __shfl_up(tv.w, 1);
  float mk1 = (lane > 0 && tv.x != pw) ? 1.f : 0.f;
  float mk3 = (tv.y != tv.x) ? 1.f : 0.f;
  float mk5 = (tv.z != tv.y) ? 1.f : 0.f;
  float mk7 = (tv.w != tv.z) ? 1.f : 0.f;
  int o1 = tv.x, o3 = tv.y, o5 = tv.z, o7 = tv.w;

  g2l16(m2b + lane * 4, &mdf[0]);
  g2l16(d2b + lane * 4, &mdf[256]);
#pragma unroll
  for (int r = 0; r < 14; ++r)
    g2l16(rowb + (size_t)r * (BB * VV), &rowbuf[r][0]);

  float a0 = (lane == 0) ? __uint_as_float((unsigned)(127 + 100) << 23) : 0.f;
  float a1 = 0.f, a2 = 0.f, a3 = 0.f, a4 = 0.f, a5 = 0.f, a6 = 0.f, a7 = 0.f, a8 = 0.f;
  float C = -100.f;

#define STEPF(t_, slot_, cp_) do {                                             \
    asm volatile("s_waitcnt vmcnt(13)" ::: "memory");                          \
    float h1 = __shfl_up(a7, 1);                                               \
    if (lane == 0) h1 = 0.f;                                                   \
    int idx_ = (t_) & 255;                                                     \
    float m2 = mdf[(cp_) * 512 + idx_];                                        \
    float d2 = mdf[(cp_) * 512 + 256 + idx_];                                  \
    const float* rb_ = &rowbuf[(slot_)][0];                                    \
    float eb = rb_[0];                                                         \
    float e1 = rb_[o1], e3 = rb_[o3], e5 = rb_[o5], e7 = rb_[o7];              \
    int tn_ = (t_) + 14; if (tn_ > TT - 1) tn_ = TT - 1;                       \
    g2l16(rowb + (size_t)tn_ * (BB * VV), &rowbuf[((slot_) + 14) & 15][0]);    \
    float pb = exp2_fast(fmaf(eb, F_L2E, -m2));                                \
    float p1 = exp2_fast(fmaf(e1, F_L2E, -m2));                                \
    float p3 = exp2_fast(fmaf(e3, F_L2E, -m2));                                \
    float p5 = exp2_fast(fmaf(e5, F_L2E, -m2));                                \
    float p7 = exp2_fast(fmaf(e7, F_L2E, -m2));                                \
    a8 = (a8 + a7) * pb;                                                       \
    a7 = (a7 + a6 + mk7 * a5) * p7;                                            \
    a6 = (a6 + a5) * pb;                                                       \
    a5 = (a5 + a4 + mk5 * a3) * p5;                                            \
    a4 = (a4 + a3) * pb;                                                       \
    a3 = (a3 + a2 + mk3 * a1) * p3;                                            \
    a2 = (a2 + a1) * pb;                                                       \
    a1 = (a1 + a0 + mk1 * h1) * p1;                                            \
    a0 = (a0 + h1) * pb;                                                       \
    C += d2;                                                                   \
  } while (0)

#define RESCALEF() do {                                                        \
    float mx = fmaxf(fmaxf(fmaxf(a0, a1), fmaxf(a2, a3)),                      \
                     fmaxf(fmaxf(a4, a5), fmaxf(fmaxf(a6, a7), a8)));          \
    mx = fmaxf(mx, __shfl_xor(mx, 1));                                         \
    mx = fmaxf(mx, __shfl_xor(mx, 2));                                         \
    mx = fmaxf(mx, __shfl_xor(mx, 4));                                         \
    mx = fmaxf(mx, __shfl_xor(mx, 8));                                         \
    mx = fmaxf(mx, __shfl_xor(mx, 16));                                        \
    mx = fmaxf(mx, __shfl_xor(mx, 32));                                        \
    int e_ = (int)((__float_as_uint(mx) >> 23) & 255) - 127;                   \
    int dl_ = 100 - e_;                                                        \
    if (dl_ > 127) dl_ = 127;                                                  \
    if (dl_ < -126) dl_ = -126;                                                \
    float sc = __uint_as_float((unsigned)(127 + dl_) << 23);                   \
    a0 *= sc; a1 *= sc; a2 *= sc; a3 *= sc; a4 *= sc;                          \
    a5 *= sc; a6 *= sc; a7 *= sc; a8 *= sc;                                    \
    C += (float)(-dl_);                                                        \
  } while (0)

  int t = 0;
  for (int c = 0; c < TT / 256 && t < len; ++c) {
    int cp = c & 1;
    if (c + 1 < TT / 256) {
      g2l16(m2b + (c + 1) * 256 + lane * 4, &mdf[(cp ^ 1) * 512]);
      g2l16(d2b + (c + 1) * 256 + lane * 4, &mdf[(cp ^ 1) * 512 + 256]);
    }
    for (int u = 0; u < 16 && t + 16 <= len; ++u) {
      STEPF(t + 0, 0, cp);  STEPF(t + 1, 1, cp);  STEPF(t + 2, 2, cp);  STEPF(t + 3, 3, cp);
      STEPF(t + 4, 4, cp);  STEPF(t + 5, 5, cp);  STEPF(t + 6, 6, cp);  STEPF(t + 7, 7, cp);
      RESCALEF();
      STEPF(t + 8, 8, cp);  STEPF(t + 9, 9, cp);  STEPF(t + 10, 10, cp); STEPF(t + 11, 11, cp);
      STEPF(t + 12, 12, cp); STEPF(t + 13, 13, cp); STEPF(t + 14, 14, cp); STEPF(t + 15, 15, cp);
      RESCALEF();
      t += 16;
    }
  }
  while (t < len) { int sl = t & 15; int cp = (t >> 8) & 1; STEPF(t, sl, cp); ++t; RESCALEF(); }

  afin[8 * lane + 0] = a0; afin[8 * lane + 1] = a1;
  afin[8 * lane + 2] = a2; afin[8 * lane + 3] = a3;
  afin[8 * lane + 4] = a4; afin[8 * lane + 5] = a5;
  afin[8 * lane + 6] = a6; afin[8 * lane + 7] = a7;
  if (lane == 63) afin[512] = a8;
  __syncthreads();
  if (lane == 0) {
    float ssum = afin[2 * tl] + afin[2 * tl - 1];
    lossw[b] = -F_LN2 * (log2_fast(ssum) + C);
  }
#undef STEPF
#undef RESCALEF
}

// ---------------- zero_infinity guard, /tl, mean ----------------
__global__ __launch_bounds__(64) void k_final(const float* __restrict__ lossw,
                                              const int* __restrict__ tlen,
                                              float* __restrict__ out) {
  int i = threadIdx.x;
  float v = lossw[i];
  float d = (float)tlen[i];
  v = (v < 1e29f && v > -1e30f) ? (v / d) : 0.f;
  v += __shfl_xor(v, 1);
  v += __shfl_xor(v, 2);
  v += __shfl_xor(v, 4);
  v += __shfl_xor(v, 8);
  v += __shfl_xor(v, 16);
  v += __shfl_xor(v, 32);
  if (i == 0) out[0] = v * (1.f / BB);
}

extern "C" void kernel_launch(void* const* d_in, const int* in_sizes, int n_in,
                              void* d_out, int out_size, void* d_ws, size_t ws_size,
                              hipStream_t stream) {
  const float* lp  = (const float*)d_in[0];
  const int* tgt   = (const int*)d_in[1];
  const int* ilen  = (const int*)d_in[2];
  const int* tlen  = (const int*)d_in[3];

  size_t e_bytes  = (size_t)TT * BB * VV * 2;        // 67.1 MB
  size_t d2_bytes = (size_t)BB * TT * 4;             // 512 KB
  size_t need     = e_bytes + 2 * d2_bytes + 1024;

  if (ws_size >= need) {
    __half* E     = (__half*)d_ws;
    float* D2T    = (float*)((char*)d_ws + e_bytes);
    float* lossw  = D2T + (size_t)BB * TT;
    k_prep<<<TT * BB / 4, 256, 0, stream>>>(lp, E, D2T);
    k_ctc2<<<BB, 64, 0, stream>>>(E, tgt, ilen, tlen, D2T, lossw);
    k_final<<<1, 64, 0, stream>>>(lossw, tlen, (float*)d_out);
  } else {
    float* M2T   = (float*)d_ws;
    float* D2T   = M2T + (size_t)BB * TT;
    float* lossw = D2T + (size_t)BB * TT;
    k_rowstats<<<TT * BB / 4, 256, 0, stream>>>(lp, M2T, D2T);
    k_ctc<<<BB, 64, 0, stream>>>(lp, tgt, ilen, tlen, M2T, D2T, lossw);
    k_final<<<1, 64, 0, stream>>>(lossw, tlen, (float*)d_out);
  }
}

// Round 4
// 204.145 us; speedup vs baseline: 3.2904x; 1.4430x over previous
//
#include <hip/hip_runtime.h>
#include <hip/hip_fp16.h>
#include <stdint.h>

// Problem constants (fixed by setup_inputs)
#define TT 2048
#define BB 64
#define VV 256
#define SS 256
#define LL 513

#define F_L2E 1.4426950408889634f
#define F_LN2 0.6931471805599453f

static __device__ __forceinline__ float exp2_fast(float x) {
  float r; asm("v_exp_f32 %0, %1" : "=v"(r) : "v"(x)); return r;
}
static __device__ __forceinline__ float log2_fast(float x) {
  float r; asm("v_log_f32 %0, %1" : "=v"(r) : "v"(x)); return r;
}
static __device__ __forceinline__ void g2l16(const void* g, void* l) {
  __builtin_amdgcn_global_load_lds((const __attribute__((address_space(1))) void*)g,
                                   (__attribute__((address_space(3))) void*)l, 16, 0, 0);
}

// ---------------------------------------------------------------------
// Phase 1: fused exp + row-sum + target-gather.
//   Eg[b][t][s]  (fp16) = exp(lp[t][b][tgt[b][s]])   s in [0,256)
//   Bl[b][t]     (f32)  = exp(lp[t][b][0])           blank prob
//   D2T[b][t]    (f32)  = -log2 sum_v exp(lp[t][b][v])
// ---------------------------------------------------------------------
__global__ __launch_bounds__(256) void k_prep2(const float* __restrict__ lp,
                                               const int* __restrict__ tgt,
                                               __half* __restrict__ Eg,
                                               float* __restrict__ Bl,
                                               float* __restrict__ D2T) {
  __shared__ int tgtl[SS];
  __shared__ __half elds[4][VV];
  int b  = blockIdx.x & (BB - 1);
  int t0 = (blockIdx.x >> 6) << 2;
  int tid = threadIdx.x;
  tgtl[tid] = tgt[b * SS + tid];
  __syncthreads();
  int w = tid >> 6, lane = tid & 63;
  int t = t0 + w;
  float4 x = reinterpret_cast<const float4*>(lp + ((size_t)t * BB + b) * VV)[lane];
  float e0 = exp2_fast(x.x * F_L2E), e1 = exp2_fast(x.y * F_L2E);
  float e2 = exp2_fast(x.z * F_L2E), e3 = exp2_fast(x.w * F_L2E);
  float z = (e0 + e1) + (e2 + e3);
  z += __shfl_xor(z, 1);
  z += __shfl_xor(z, 2);
  z += __shfl_xor(z, 4);
  z += __shfl_xor(z, 8);
  z += __shfl_xor(z, 16);
  z += __shfl_xor(z, 32);
  elds[w][4 * lane + 0] = __float2half_rn(e0);
  elds[w][4 * lane + 1] = __float2half_rn(e1);
  elds[w][4 * lane + 2] = __float2half_rn(e2);
  elds[w][4 * lane + 3] = __float2half_rn(e3);
  asm volatile("s_waitcnt lgkmcnt(0)" ::: "memory");   // wave-local write->read
  int s = 4 * lane;
  union { __half h[4]; uint2 u; } pk;
  pk.h[0] = elds[w][tgtl[s + 0]];
  pk.h[1] = elds[w][tgtl[s + 1]];
  pk.h[2] = elds[w][tgtl[s + 2]];
  pk.h[3] = elds[w][tgtl[s + 3]];
  reinterpret_cast<uint2*>(Eg + ((size_t)b * TT + t) * SS)[lane] = pk.u;
  if (lane == 0) {
    Bl[(size_t)b * TT + t]  = e0;
    D2T[(size_t)b * TT + t] = -log2_fast(z);
  }
}

// ---------------------------------------------------------------------
// Phase 2: linear-domain CTC DP, f64 alpha (no clipping), one wave/batch.
// Per-step data = one coalesced global_load_dwordx2 (register-pipelined,
// 16-deep, vmcnt(16) per 16-step block) + LDS broadcast of blank prob.
// ---------------------------------------------------------------------
__global__ __launch_bounds__(64) void k_ctc3(const __half* __restrict__ Eg,
                                             const float* __restrict__ Bl,
                                             const int* __restrict__ tgt,
                                             const int* __restrict__ ilen,
                                             const int* __restrict__ tlen,
                                             const float* __restrict__ D2T,
                                             float* __restrict__ lossw) {
  __shared__ float  blanklds[TT];   // 8 KB
  __shared__ double afin[LL];       // 4.1 KB
  int b = blockIdx.x, lane = threadIdx.x;
  int len = ilen[b]; if (len > TT) len = TT; if (len < 0) len = 0;
  int tl  = tlen[b]; if (tl > SS) tl = SS; if (tl < 1) tl = 1;

  const float* blb = Bl  + (size_t)b * TT;
  const float* d2b = D2T + (size_t)b * TT;
  const uint2* eq  = reinterpret_cast<const uint2*>(Eg) + (size_t)b * TT * 64 + lane;

  int4 tv = reinterpret_cast<const int4*>(tgt + b * SS)[lane];
  int pw  = __shfl_up(tv.w, 1);
  double mk1 = (lane > 0 && tv.x != pw) ? 1.0 : 0.0;
  double mk3 = (tv.y != tv.x) ? 1.0 : 0.0;
  double mk5 = (tv.z != tv.y) ? 1.0 : 0.0;
  double mk7 = (tv.w != tv.z) ? 1.0 : 0.0;

  // stage blank column (8 KB) into LDS
#pragma unroll
  for (int j = 0; j < 8; ++j)
    g2l16(blb + j * 256 + lane * 4, &blanklds[j * 256]);

  uint2 pfA[16], pfB[16];
#pragma unroll
  for (int j = 0; j < 16; ++j) pfA[j] = eq[(size_t)j * 64];
  asm volatile("s_waitcnt vmcnt(0)" ::: "memory");     // one-time drain

  // alpha with 2^512 bias; exponent carried exactly in C (log2 units)
  double a0 = (lane == 0) ? __longlong_as_double(0x5FF0000000000000LL) : 0.0;
  double a1 = 0, a2 = 0, a3 = 0, a4 = 0, a5 = 0, a6 = 0, a7 = 0, a8 = 0;
  float C = -512.f;

#define STEP64(BANK, J, TB) do {                                               \
    uint2 pv = pf##BANK[J];                                                    \
    float2 flo = __half22float2(*reinterpret_cast<const __half2*>(&pv.x));     \
    float2 fhi = __half22float2(*reinterpret_cast<const __half2*>(&pv.y));     \
    double pb = (double)blanklds[(TB) + (J)];                                  \
    double q1 = (double)flo.x, q3 = (double)flo.y;                             \
    double q5 = (double)fhi.x, q7 = (double)fhi.y;                             \
    double h1 = __shfl_up(a7, 1);                                              \
    h1 = (lane == 0) ? 0.0 : h1;                                               \
    a8 = (a8 + a7) * pb;                                                       \
    a7 = (a7 + a6 + mk7 * a5) * q7;                                            \
    a6 = (a6 + a5) * pb;                                                       \
    a5 = (a5 + a4 + mk5 * a3) * q5;                                            \
    a4 = (a4 + a3) * pb;                                                       \
    a3 = (a3 + a2 + mk3 * a1) * q3;                                            \
    a2 = (a2 + a1) * pb;                                                       \
    a1 = (a1 + a0 + mk1 * h1) * q1;                                            \
    a0 = (a0 + h1) * pb;                                                       \
  } while (0)

#define ISSUE16(BANK, TBN) do {                                                \
    const uint2* p_ = eq + (size_t)(TBN) * 64;                                 \
    _Pragma("unroll")                                                          \
    for (int j_ = 0; j_ < 16; ++j_) pf##BANK[j_] = p_[(size_t)j_ * 64];        \
  } while (0)

#define BLK16(CUR, NXT, TB) do {                                               \
    int tbn_ = (TB) + 16; if (tbn_ > TT - 16) tbn_ = TT - 16;                  \
    ISSUE16(NXT, tbn_);                                                        \
    asm volatile("s_waitcnt vmcnt(16)" ::: "memory");                          \
    STEP64(CUR, 0, (TB));  STEP64(CUR, 1, (TB));  STEP64(CUR, 2, (TB));        \
    STEP64(CUR, 3, (TB));  STEP64(CUR, 4, (TB));  STEP64(CUR, 5, (TB));        \
    STEP64(CUR, 6, (TB));  STEP64(CUR, 7, (TB));  STEP64(CUR, 8, (TB));        \
    STEP64(CUR, 9, (TB));  STEP64(CUR, 10, (TB)); STEP64(CUR, 11, (TB));       \
    STEP64(CUR, 12, (TB)); STEP64(CUR, 13, (TB)); STEP64(CUR, 14, (TB));       \
    STEP64(CUR, 15, (TB));                                                     \
  } while (0)

  // rescale band max back to 2^512 every 32 steps; exact exponent into C
#define RESCALE64() do {                                                       \
    double mx = fmax(fmax(fmax(a0, a1), fmax(a2, a3)),                         \
                     fmax(fmax(a4, a5), fmax(fmax(a6, a7), a8)));              \
    mx = fmax(mx, __shfl_xor(mx, 1));                                          \
    mx = fmax(mx, __shfl_xor(mx, 2));                                          \
    mx = fmax(mx, __shfl_xor(mx, 4));                                          \
    mx = fmax(mx, __shfl_xor(mx, 8));                                          \
    mx = fmax(mx, __shfl_xor(mx, 16));                                         \
    mx = fmax(mx, __shfl_xor(mx, 32));                                         \
    int eb_ = (int)((__double_as_longlong(mx) >> 52) & 0x7ff);                 \
    int k_ = 1535 - eb_;                                                       \
    if (k_ > 1023) k_ = 1023; if (k_ < -1022) k_ = -1022;                      \
    double sc_ = __longlong_as_double((long long)(1023 + k_) << 52);           \
    a0 *= sc_; a1 *= sc_; a2 *= sc_; a3 *= sc_; a4 *= sc_;                     \
    a5 *= sc_; a6 *= sc_; a7 *= sc_; a8 *= sc_;                                \
    C -= (float)k_;                                                            \
  } while (0)

  int tcur = 0;
  for (int g = 0; g < TT / 32 && tcur + 32 <= len; ++g) {
    BLK16(A, B, tcur);
    BLK16(B, A, tcur + 16);
    tcur += 32;
    RESCALE64();
  }

  // generic tail (len not a multiple of 32; not hit for this shape)
  if (tcur < len) {
    asm volatile("s_waitcnt vmcnt(0)" ::: "memory");
    while (tcur < len) {
      uint2 pv = eq[(size_t)tcur * 64];
      float2 flo = __half22float2(*reinterpret_cast<const __half2*>(&pv.x));
      float2 fhi = __half22float2(*reinterpret_cast<const __half2*>(&pv.y));
      double pb = (double)blanklds[tcur];
      double q1 = flo.x, q3 = flo.y, q5 = fhi.x, q7 = fhi.y;
      double h1 = __shfl_up(a7, 1); h1 = (lane == 0) ? 0.0 : h1;
      a8 = (a8 + a7) * pb;
      a7 = (a7 + a6 + mk7 * a5) * q7;
      a6 = (a6 + a5) * pb;
      a5 = (a5 + a4 + mk5 * a3) * q5;
      a4 = (a4 + a3) * pb;
      a3 = (a3 + a2 + mk3 * a1) * q3;
      a2 = (a2 + a1) * pb;
      a1 = (a1 + a0 + mk1 * h1) * q1;
      a0 = (a0 + h1) * pb;
      ++tcur;
      RESCALE64();
    }
  }

  // normalization constant: sum of -log2(Z_t) over t < len
  float dsm = 0.f;
  for (int k2 = 0; k2 < TT / 64; ++k2) {
    int t2 = lane + 64 * k2;
    if (t2 < len) dsm += d2b[t2];
  }
  dsm += __shfl_xor(dsm, 1);
  dsm += __shfl_xor(dsm, 2);
  dsm += __shfl_xor(dsm, 4);
  dsm += __shfl_xor(dsm, 8);
  dsm += __shfl_xor(dsm, 16);
  dsm += __shfl_xor(dsm, 32);

  afin[8 * lane + 0] = a0; afin[8 * lane + 1] = a1;
  afin[8 * lane + 2] = a2; afin[8 * lane + 3] = a3;
  afin[8 * lane + 4] = a4; afin[8 * lane + 5] = a5;
  afin[8 * lane + 6] = a6; afin[8 * lane + 7] = a7;
  if (lane == 63) afin[512] = a8;
  __syncthreads();
  if (lane == 0) {
    double ssum = afin[2 * tl] + afin[2 * tl - 1];
    long long bt = __double_as_longlong(ssum);
    int ex = (int)((bt >> 52) & 0x7ff) - 1023;
    double mant = __longlong_as_double((bt & 0xFFFFFFFFFFFFFLL) | 0x3FF0000000000000LL);
    float lm = log2_fast((float)mant);
    lossw[b] = -F_LN2 * (lm + (float)ex + C + dsm);
  }
#undef STEP64
#undef ISSUE16
#undef BLK16
#undef RESCALE64
}

// ---------------- zero_infinity guard, /tl, mean ----------------
__global__ __launch_bounds__(64) void k_final(const float* __restrict__ lossw,
                                              const int* __restrict__ tlen,
                                              float* __restrict__ out) {
  int i = threadIdx.x;
  float v = lossw[i];
  float d = (float)tlen[i];
  v = (v < 1e29f && v > -1e30f) ? (v / d) : 0.f;
  v += __shfl_xor(v, 1);
  v += __shfl_xor(v, 2);
  v += __shfl_xor(v, 4);
  v += __shfl_xor(v, 8);
  v += __shfl_xor(v, 16);
  v += __shfl_xor(v, 32);
  if (i == 0) out[0] = v * (1.f / BB);
}

extern "C" void kernel_launch(void* const* d_in, const int* in_sizes, int n_in,
                              void* d_out, int out_size, void* d_ws, size_t ws_size,
                              hipStream_t stream) {
  const float* lp = (const float*)d_in[0];
  const int* tgt  = (const int*)d_in[1];
  const int* ilen = (const int*)d_in[2];
  const int* tlen = (const int*)d_in[3];

  size_t eg_bytes = (size_t)BB * TT * SS * 2;          // 64 MB
  __half* Eg   = (__half*)d_ws;
  float* Bl    = (float*)((char*)d_ws + eg_bytes);     // [B][T]
  float* D2T   = Bl + (size_t)BB * TT;                 // [B][T]
  float* lossw = D2T + (size_t)BB * TT;                // [B]

  k_prep2<<<BB * (TT / 4), 256, 0, stream>>>(lp, tgt, Eg, Bl, D2T);
  k_ctc3<<<BB, 64, 0, stream>>>(Eg, Bl, tgt, ilen, tlen, D2T, lossw);
  k_final<<<1, 64, 0, stream>>>(lossw, tlen, (float*)d_out);
}

// Round 7
// 163.290 us; speedup vs baseline: 4.1137x; 1.2502x over previous
//
#include <hip/hip_runtime.h>
#include <hip/hip_fp16.h>
#include <stdint.h>

// Problem constants (fixed by setup_inputs)
#define TT 2048
#define BB 64
#define VV 256
#define SS 256
#define LL 513

#define F_L2E 1.4426950408889634f
#define F_LN2 0.6931471805599453f

static __device__ __forceinline__ float exp2_fast(float x) {
  float r; asm("v_exp_f32 %0, %1" : "=v"(r) : "v"(x)); return r;
}
static __device__ __forceinline__ float log2_fast(float x) {
  float r; asm("v_log_f32 %0, %1" : "=v"(r) : "v"(x)); return r;
}
static __device__ __forceinline__ void g2l16(const void* g, void* l) {
  __builtin_amdgcn_global_load_lds((const __attribute__((address_space(1))) void*)g,
                                   (__attribute__((address_space(3))) void*)l, 16, 0, 0);
}
// wave_shr:1 on a double via two 32-bit DPP moves. Lane i gets lane i-1's value;
// lane 0 gets 0.0 (bound_ctrl zeroes both halves). Pure VALU — no LDS latency.
static __device__ __forceinline__ double dpp_shr1_d(double x) {
  union { double d; int i[2]; } u; u.d = x;
  int lo = __builtin_amdgcn_update_dpp(0, u.i[0], 0x138, 0xF, 0xF, true);
  int hi = __builtin_amdgcn_update_dpp(0, u.i[1], 0x138, 0xF, 0xF, true);
  union { int i[2]; double d; } r; r.i[0] = lo; r.i[1] = hi;
  return r.d;
}
// wave-wide int max step (DPP ctrl as template const); valid result in lane 63
// after the 0x111/0x112/0x114/0x118/0x142/0x143 sequence.
template <int CTRL>
static __device__ __forceinline__ int dppmax_i(int v) {
  int d = __builtin_amdgcn_update_dpp(v, v, CTRL, 0xF, 0xF, false);
  return v > d ? v : d;
}

// ---------------------------------------------------------------------
// Phase 1: fused exp + row-sum + target-gather.
//   Eg[b][t][s]  (fp16) = exp(lp[t][b][tgt[b][s]])   s in [0,256)
//   Bl[b][t]     (f32)  = exp(lp[t][b][0])           blank prob
//   D2T[b][t]    (f32)  = -log2 sum_v exp(lp[t][b][v])
// ---------------------------------------------------------------------
__global__ __launch_bounds__(256) void k_prep2(const float* __restrict__ lp,
                                               const int* __restrict__ tgt,
                                               __half* __restrict__ Eg,
                                               float* __restrict__ Bl,
                                               float* __restrict__ D2T) {
  __shared__ int tgtl[SS];
  __shared__ __half elds[4][VV];
  int b  = blockIdx.x & (BB - 1);
  int t0 = (blockIdx.x >> 6) << 2;
  int tid = threadIdx.x;
  tgtl[tid] = tgt[b * SS + tid];
  __syncthreads();
  int w = tid >> 6, lane = tid & 63;
  int t = t0 + w;
  float4 x = reinterpret_cast<const float4*>(lp + ((size_t)t * BB + b) * VV)[lane];
  float e0 = exp2_fast(x.x * F_L2E), e1 = exp2_fast(x.y * F_L2E);
  float e2 = exp2_fast(x.z * F_L2E), e3 = exp2_fast(x.w * F_L2E);
  float z = (e0 + e1) + (e2 + e3);
  z += __shfl_xor(z, 1);
  z += __shfl_xor(z, 2);
  z += __shfl_xor(z, 4);
  z += __shfl_xor(z, 8);
  z += __shfl_xor(z, 16);
  z += __shfl_xor(z, 32);
  elds[w][4 * lane + 0] = __float2half_rn(e0);
  elds[w][4 * lane + 1] = __float2half_rn(e1);
  elds[w][4 * lane + 2] = __float2half_rn(e2);
  elds[w][4 * lane + 3] = __float2half_rn(e3);
  asm volatile("s_waitcnt lgkmcnt(0)" ::: "memory");   // wave-local write->read
  int s = 4 * lane;
  union { __half h[4]; uint2 u; } pk;
  pk.h[0] = elds[w][tgtl[s + 0]];
  pk.h[1] = elds[w][tgtl[s + 1]];
  pk.h[2] = elds[w][tgtl[s + 2]];
  pk.h[3] = elds[w][tgtl[s + 3]];
  reinterpret_cast<uint2*>(Eg + ((size_t)b * TT + t) * SS)[lane] = pk.u;
  if (lane == 0) {
    Bl[(size_t)b * TT + t]  = e0;
    D2T[(size_t)b * TT + t] = -log2_fast(z);
  }
}

// ---------------------------------------------------------------------
// Phase 2: f64-alpha CTC DP (no clipping), one wave/batch.
// R4 structure; cross-lane ops now DPP-only (no LDS in the hot loop).
// ---------------------------------------------------------------------
__global__ __launch_bounds__(64) void k_ctc5(const __half* __restrict__ Eg,
                                             const float* __restrict__ Bl,
                                             const int* __restrict__ tgt,
                                             const int* __restrict__ ilen,
                                             const int* __restrict__ tlen,
                                             const float* __restrict__ D2T,
                                             float* __restrict__ lossw) {
  __shared__ float  blanklds[TT];   // 8 KB
  __shared__ double afin[LL];       // 4.1 KB
  int b = blockIdx.x, lane = threadIdx.x;
  int len = ilen[b]; if (len > TT) len = TT; if (len < 0) len = 0;
  int tl  = tlen[b]; if (tl > SS) tl = SS; if (tl < 1) tl = 1;

  const float* blb = Bl  + (size_t)b * TT;
  const float* d2b = D2T + (size_t)b * TT;
  const uint2* eq  = reinterpret_cast<const uint2*>(Eg) + (size_t)b * TT * 64 + lane;

  int4 tv = reinterpret_cast<const int4*>(tgt + b * SS)[lane];
  int pw  = __shfl_up(tv.w, 1);
  double mk1 = (lane > 0 && tv.x != pw) ? 1.0 : 0.0;
  double mk3 = (tv.y != tv.x) ? 1.0 : 0.0;
  double mk5 = (tv.z != tv.y) ? 1.0 : 0.0;
  double mk7 = (tv.w != tv.z) ? 1.0 : 0.0;

  // stage blank column (8 KB) into LDS
#pragma unroll
  for (int j = 0; j < 8; ++j)
    g2l16(blb + j * 256 + lane * 4, &blanklds[j * 256]);

  uint2 pfA[16], pfB[16];
#pragma unroll
  for (int j = 0; j < 16; ++j) pfA[j] = eq[(size_t)j * 64];
  asm volatile("s_waitcnt vmcnt(0)" ::: "memory");     // one-time drain

  // alpha with 2^512 bias; exponent carried exactly in C (log2 units)
  double a0 = (lane == 0) ? __longlong_as_double(0x5FF0000000000000LL) : 0.0;
  double a1 = 0, a2 = 0, a3 = 0, a4 = 0, a5 = 0, a6 = 0, a7 = 0, a8 = 0;
  float C = -512.f;

#define STEP64(BANK, J, TB) do {                                               \
    uint2 pv = pf##BANK[J];                                                    \
    float2 flo = __half22float2(*reinterpret_cast<const __half2*>(&pv.x));     \
    float2 fhi = __half22float2(*reinterpret_cast<const __half2*>(&pv.y));     \
    double pb = (double)blanklds[(TB) + (J)];                                  \
    double q1 = (double)flo.x, q3 = (double)flo.y;                             \
    double q5 = (double)fhi.x, q7 = (double)fhi.y;                             \
    double h1 = dpp_shr1_d(a7);                                                \
    a8 = (a8 + a7) * pb;                                                       \
    a7 = (a7 + a6 + mk7 * a5) * q7;                                            \
    a6 = (a6 + a5) * pb;                                                       \
    a5 = (a5 + a4 + mk5 * a3) * q5;                                            \
    a4 = (a4 + a3) * pb;                                                       \
    a3 = (a3 + a2 + mk3 * a1) * q3;                                            \
    a2 = (a2 + a1) * pb;                                                       \
    a1 = (a1 + a0 + mk1 * h1) * q1;                                            \
    a0 = (a0 + h1) * pb;                                                       \
  } while (0)

#define ISSUE16(BANK, TBN) do {                                                \
    const uint2* p_ = eq + (size_t)(TBN) * 64;                                 \
    _Pragma("unroll")                                                          \
    for (int j_ = 0; j_ < 16; ++j_) pf##BANK[j_] = p_[(size_t)j_ * 64];        \
  } while (0)

#define BLK16(CUR, NXT, TB) do {                                               \
    int tbn_ = (TB) + 16; if (tbn_ > TT - 16) tbn_ = TT - 16;                  \
    ISSUE16(NXT, tbn_);                                                        \
    asm volatile("s_waitcnt vmcnt(16)" ::: "memory");                          \
    STEP64(CUR, 0, (TB));  STEP64(CUR, 1, (TB));  STEP64(CUR, 2, (TB));        \
    STEP64(CUR, 3, (TB));  STEP64(CUR, 4, (TB));  STEP64(CUR, 5, (TB));        \
    STEP64(CUR, 6, (TB));  STEP64(CUR, 7, (TB));  STEP64(CUR, 8, (TB));        \
    STEP64(CUR, 9, (TB));  STEP64(CUR, 10, (TB)); STEP64(CUR, 11, (TB));       \
    STEP64(CUR, 12, (TB)); STEP64(CUR, 13, (TB)); STEP64(CUR, 14, (TB));       \
    STEP64(CUR, 15, (TB));                                                     \
  } while (0)

  // rescale band max back to 2^512 every 32 steps; exponent reduce via int DPP
  // (row_shr 1/2/4/8 + row_bcast15/31 -> lane 63, readlane), exact shift into C.
#define RESCALE64() do {                                                       \
    double mx = fmax(fmax(fmax(a0, a1), fmax(a2, a3)),                         \
                     fmax(fmax(a4, a5), fmax(fmax(a6, a7), a8)));              \
    int e_ = (int)((__double_as_longlong(mx) >> 52) & 0x7ff);                  \
    e_ = dppmax_i<0x111>(e_); e_ = dppmax_i<0x112>(e_);                        \
    e_ = dppmax_i<0x114>(e_); e_ = dppmax_i<0x118>(e_);                        \
    e_ = dppmax_i<0x142>(e_); e_ = dppmax_i<0x143>(e_);                        \
    int eg_ = __builtin_amdgcn_readlane(e_, 63);                               \
    int k_ = 1535 - eg_;                                                       \
    if (k_ > 1023) k_ = 1023; if (k_ < -1022) k_ = -1022;                      \
    double sc_ = __longlong_as_double((long long)(1023 + k_) << 52);           \
    a0 *= sc_; a1 *= sc_; a2 *= sc_; a3 *= sc_; a4 *= sc_;                     \
    a5 *= sc_; a6 *= sc_; a7 *= sc_; a8 *= sc_;                                \
    C -= (float)k_;                                                            \
  } while (0)

  int tcur = 0;
  for (int g = 0; g < TT / 32 && tcur + 32 <= len; ++g) {
    BLK16(A, B, tcur);
    BLK16(B, A, tcur + 16);
    tcur += 32;
    RESCALE64();
  }

  // generic tail (len not a multiple of 32; not hit for this shape)
  if (tcur < len) {
    asm volatile("s_waitcnt vmcnt(0)" ::: "memory");
    while (tcur < len) {
      uint2 pv = eq[(size_t)tcur * 64];
      float2 flo = __half22float2(*reinterpret_cast<const __half2*>(&pv.x));
      float2 fhi = __half22float2(*reinterpret_cast<const __half2*>(&pv.y));
      double pb = (double)blanklds[tcur];
      double q1 = flo.x, q3 = flo.y, q5 = fhi.x, q7 = fhi.y;
      double h1 = dpp_shr1_d(a7);
      a8 = (a8 + a7) * pb;
      a7 = (a7 + a6 + mk7 * a5) * q7;
      a6 = (a6 + a5) * pb;
      a5 = (a5 + a4 + mk5 * a3) * q5;
      a4 = (a4 + a3) * pb;
      a3 = (a3 + a2 + mk3 * a1) * q3;
      a2 = (a2 + a1) * pb;
      a1 = (a1 + a0 + mk1 * h1) * q1;
      a0 = (a0 + h1) * pb;
      ++tcur;
      if ((tcur & 31) == 0) RESCALE64();
    }
  }

  // normalization constant: sum of -log2(Z_t) over t < len
  float dsm = 0.f;
  for (int k2 = 0; k2 < TT / 64; ++k2) {
    int t2 = lane + 64 * k2;
    if (t2 < len) dsm += d2b[t2];
  }
  dsm += __shfl_xor(dsm, 1);
  dsm += __shfl_xor(dsm, 2);
  dsm += __shfl_xor(dsm, 4);
  dsm += __shfl_xor(dsm, 8);
  dsm += __shfl_xor(dsm, 16);
  dsm += __shfl_xor(dsm, 32);

  afin[8 * lane + 0] = a0; afin[8 * lane + 1] = a1;
  afin[8 * lane + 2] = a2; afin[8 * lane + 3] = a3;
  afin[8 * lane + 4] = a4; afin[8 * lane + 5] = a5;
  afin[8 * lane + 6] = a6; afin[8 * lane + 7] = a7;
  if (lane == 63) afin[512] = a8;
  __syncthreads();
  if (lane == 0) {
    double ssum = afin[2 * tl] + afin[2 * tl - 1];
    long long bt = __double_as_longlong(ssum);
    int ex = (int)((bt >> 52) & 0x7ff) - 1023;
    double mant = __longlong_as_double((bt & 0xFFFFFFFFFFFFFLL) | 0x3FF0000000000000LL);
    float lm = log2_fast((float)mant);
    lossw[b] = -F_LN2 * (lm + (float)ex + C + dsm);
  }
#undef STEP64
#undef ISSUE16
#undef BLK16
#undef RESCALE64
}

// ---------------- zero_infinity guard, /tl, mean ----------------
__global__ __launch_bounds__(64) void k_final(const float* __restrict__ lossw,
                                              const int* __restrict__ tlen,
                                              float* __restrict__ out) {
  int i = threadIdx.x;
  float v = lossw[i];
  float d = (float)tlen[i];
  v = (v < 1e29f && v > -1e30f) ? (v / d) : 0.f;
  v += __shfl_xor(v, 1);
  v += __shfl_xor(v, 2);
  v += __shfl_xor(v, 4);
  v += __shfl_xor(v, 8);
  v += __shfl_xor(v, 16);
  v += __shfl_xor(v, 32);
  if (i == 0) out[0] = v * (1.f / BB);
}

extern "C" void kernel_launch(void* const* d_in, const int* in_sizes, int n_in,
                              void* d_out, int out_size, void* d_ws, size_t ws_size,
                              hipStream_t stream) {
  const float* lp = (const float*)d_in[0];
  const int* tgt  = (const int*)d_in[1];
  const int* ilen = (const int*)d_in[2];
  const int* tlen = (const int*)d_in[3];

  size_t eg_bytes = (size_t)BB * TT * SS * 2;          // 64 MB
  __half* Eg   = (__half*)d_ws;
  float* Bl    = (float*)((char*)d_ws + eg_bytes);     // [B][T]
  float* D2T   = Bl + (size_t)BB * TT;                 // [B][T]
  float* lossw = D2T + (size_t)BB * TT;                // [B]

  k_prep2<<<BB * (TT / 4), 256, 0, stream>>>(lp, tgt, Eg, Bl, D2T);
  k_ctc5<<<BB, 64, 0, stream>>>(Eg, Bl, tgt, ilen, tlen, D2T, lossw);
  k_final<<<1, 64, 0, stream>>>(lossw, tlen, (float*)d_out);
}